// Round 5
// baseline (209.221 us; speedup 1.0000x reference)
//
#include <hip/hip_runtime.h>
#include <hip/hip_bf16.h>

// RandomProjectionQuantizer — attribution-proof MFMA screening + exact rescore (R5).
//  x:(16,2048,320) f32, mask:(16,2048) i32 (exactly 16384 ones),
//  W:(16,320) f32, codebook:(8192,16) f32 -> scalar int32 label
//
//  Screening folds the FULL distance into the MFMA dot:
//    A~ = [t(16), 1, 1, h1, h2, 0..]  (h1+h2 = bf16-split of t2)
//    C~ = [-2c(16), g1, g2, 1, 1, 0..] (g1+g2 = bf16-split of c2)
//  so D[i][j] = t2 + c2 - 2 t.c for SOME (i,j) — immune to any lane->row/col
//  attribution; per-strip (32 rows) wave-wide min uses no attribution at all.
//  Gate: strip passes iff A_s - eps_s <= T = min_s(A_s + eps_s).

#define NMASK   16384
#define D       320
#define CDIM    16
#define NCODES  8192
#define EPS_C   0.016875f    // 1.08 * 2^-6
#define EPS_ABS 0.05f

typedef __attribute__((ext_vector_type(8))) short short8;
typedef __attribute__((ext_vector_type(4))) float f32x4;

__device__ inline unsigned int encf(float f) {
  unsigned int u = __float_as_uint(f);
  return (u & 0x80000000u) ? ~u : (u | 0x80000000u);
}
__device__ inline float decf(unsigned int u) {
  unsigned int b = (u & 0x80000000u) ? (u & 0x7fffffffu) : ~u;
  return __uint_as_float(b);
}
__device__ inline unsigned short f2bf(float f) {   // RNE f32->bf16
  unsigned int u = __float_as_uint(f);
  unsigned int r = u + 0x7fffu + ((u >> 16) & 1u);
  return (unsigned short)(r >> 16);
}
__device__ inline float bf2f(unsigned short h) {
  return __uint_as_float(((unsigned int)h) << 16);
}

// shared projection chain: 4 lanes/row (chunk ch of 80), butterfly combine.
// Used bit-identically by project and rescore.
__device__ inline void proj_row(const float* __restrict__ x,
                                const float* __restrict__ W,
                                int row, int ch, float pd[16]) {
#pragma unroll
  for (int c = 0; c < 16; ++c) pd[c] = 0.f;
  const float4* xp = (const float4*)(x + (size_t)row * D + ch * 80);
#pragma unroll 4
  for (int j = 0; j < 20; ++j) {
    float4 xv = xp[j];
#pragma unroll
    for (int c = 0; c < 16; ++c) {
      const float4 wv = *(const float4*)(W + c * D + ch * 80 + j * 4);
      float acc = fmaf(xv.x, wv.x, pd[c]);
      acc = fmaf(xv.y, wv.y, acc);
      acc = fmaf(xv.z, wv.z, acc);
      pd[c] = fmaf(xv.w, wv.w, acc);
    }
  }
#pragma unroll
  for (int c = 0; c < 16; ++c) {
    pd[c] += __shfl_xor(pd[c], 1);
    pd[c] += __shfl_xor(pd[c], 2);
  }
}

// ---------------- Kernel 1: prep (80 blocks x 512) ---------------------------
__global__ __launch_bounds__(512) void prep_kernel(
    const int* __restrict__ mask, const float* __restrict__ cbk,
    unsigned int* __restrict__ chunksum, int* __restrict__ chunkpref,
    float* __restrict__ c2, unsigned short* __restrict__ cbf32,
    float* __restrict__ pmax_c2, unsigned int* __restrict__ strip_a_u,
    unsigned int* __restrict__ stripmax_u, unsigned long long* __restrict__ key,
    unsigned int* __restrict__ prepctr) {
  __shared__ int lastf;
  int tid = threadIdx.x, bid = (int)blockIdx.x;
  if (bid < 64) {                                   // 64 blocks x 8 waves = 512 chunks
    int wv = tid >> 6, lane = tid & 63;
    int c = bid * 8 + wv;
    int m = mask[c * 64 + lane];
    unsigned long long bal = __ballot(m != 0);
    if (lane == 0) atomicExch(&chunksum[c], (unsigned int)__popcll(bal));
  } else {                                          // 16 blocks x 512 codes
    __shared__ float sm[512];
    int b = bid - 64;
    int k = b * 512 + tid;
    const float4* p = (const float4*)(cbk + (long)k * CDIM);
    float s = 0.f; unsigned short nb[16];
#pragma unroll
    for (int q = 0; q < 4; ++q) {
      float4 v = p[q];
      s = fmaf(v.x, v.x, s); s = fmaf(v.y, v.y, s);
      s = fmaf(v.z, v.z, s); s = fmaf(v.w, v.w, s);
      nb[q*4+0] = f2bf(-2.0f * v.x); nb[q*4+1] = f2bf(-2.0f * v.y);
      nb[q*4+2] = f2bf(-2.0f * v.z); nb[q*4+3] = f2bf(-2.0f * v.w);
    }
    c2[k] = s;
    unsigned short g1 = f2bf(s);
    unsigned short g2 = f2bf(s - bf2f(g1));
    uint4 pk0, pk1, pk2, pk3;
    pk0.x = (unsigned int)nb[0]  | ((unsigned int)nb[1]  << 16);
    pk0.y = (unsigned int)nb[2]  | ((unsigned int)nb[3]  << 16);
    pk0.z = (unsigned int)nb[4]  | ((unsigned int)nb[5]  << 16);
    pk0.w = (unsigned int)nb[6]  | ((unsigned int)nb[7]  << 16);
    pk1.x = (unsigned int)nb[8]  | ((unsigned int)nb[9]  << 16);
    pk1.y = (unsigned int)nb[10] | ((unsigned int)nb[11] << 16);
    pk1.z = (unsigned int)nb[12] | ((unsigned int)nb[13] << 16);
    pk1.w = (unsigned int)nb[14] | ((unsigned int)nb[15] << 16);
    pk2.x = (unsigned int)g1 | ((unsigned int)g2 << 16); // dims 16,17: g1,g2
    pk2.y = 0x3F803F80u;                                 // dims 18,19: 1,1
    pk2.z = 0u; pk2.w = 0u;
    pk3.x = 0u; pk3.y = 0u; pk3.z = 0u; pk3.w = 0u;
    uint4* dst = (uint4*)(cbf32 + (long)k * 32);
    dst[0] = pk0; dst[1] = pk1; dst[2] = pk2; dst[3] = pk3;
    if (b == 0) {
      strip_a_u[tid]  = 0xFFFFFFFFu;
      stripmax_u[tid] = 0u;
      if (tid == 0) key[0] = 0xFFFFFFFFFFFFFFFFull;
    }
    sm[tid] = s; __syncthreads();
    for (int st = 256; st > 0; st >>= 1) {
      if (tid < st) sm[tid] = fmaxf(sm[tid], sm[tid + st]);
      __syncthreads();
    }
    if (tid == 0) pmax_c2[b] = sm[0];
  }
  __threadfence();
  __syncthreads();
  if (tid == 0) lastf = (atomicAdd(prepctr, 1u) == 79u) ? 1 : 0;
  __syncthreads();
  if (lastf) {                                      // last block: 512-chunk scan
    __shared__ int a[512], bb[512];
    a[tid] = (int)atomicAdd(&chunksum[tid], 0u);
    __syncthreads();
    int *src = a, *dst = bb;
    for (int off = 1; off < 512; off <<= 1) {
      dst[tid] = src[tid] + (tid >= off ? src[tid - off] : 0);
      __syncthreads();
      int* t = src; src = dst; dst = t;
    }
    chunkpref[tid] = (tid == 0) ? 0 : src[tid - 1];
  }
}

// ---------------- Kernel 2: project (512 blocks x 256) -----------------------
__global__ __launch_bounds__(256) void project_kernel(
    const float* __restrict__ x, const int* __restrict__ mask,
    const int* __restrict__ chunkpref, const float* __restrict__ W,
    unsigned short* __restrict__ tbf32, int* __restrict__ origrow,
    unsigned int* __restrict__ stripmax_u) {
  __shared__ unsigned long long mb;
  int tid = threadIdx.x, bid = (int)blockIdx.x;
  int base = bid * 64;
  if (tid < 64) {
    int m = mask[base + tid];
    unsigned long long bal = __ballot(m != 0);
    if (tid == 0) mb = bal;
  }
  __syncthreads();
  unsigned long long B0 = mb;
  int r = tid >> 2, ch = tid & 3;
  int row = base + r;
  int m = (int)((B0 >> r) & 1ull);
  if (!m) return;
  float pd[16];
  proj_row(x, W, row, ch, pd);
  if (ch == 0) {
    int rank = chunkpref[bid] + __popcll(B0 & ((1ull << r) - 1ull));
    float t2 = 0.f;
#pragma unroll
    for (int c = 0; c < 16; ++c) t2 = fmaf(pd[c], pd[c], t2);
    origrow[rank] = row;
    atomicMax(&stripmax_u[rank >> 5], __float_as_uint(t2)); // t2>=0: raw bits monotone
    unsigned short tb[16];
#pragma unroll
    for (int c = 0; c < 16; ++c) tb[c] = f2bf(pd[c]);
    unsigned short h1 = f2bf(t2);
    unsigned short h2 = f2bf(t2 - bf2f(h1));
    uint4 pk0, pk1, pk2, pk3;
    pk0.x = (unsigned int)tb[0]  | ((unsigned int)tb[1]  << 16);
    pk0.y = (unsigned int)tb[2]  | ((unsigned int)tb[3]  << 16);
    pk0.z = (unsigned int)tb[4]  | ((unsigned int)tb[5]  << 16);
    pk0.w = (unsigned int)tb[6]  | ((unsigned int)tb[7]  << 16);
    pk1.x = (unsigned int)tb[8]  | ((unsigned int)tb[9]  << 16);
    pk1.y = (unsigned int)tb[10] | ((unsigned int)tb[11] << 16);
    pk1.z = (unsigned int)tb[12] | ((unsigned int)tb[13] << 16);
    pk1.w = (unsigned int)tb[14] | ((unsigned int)tb[15] << 16);
    pk2.x = 0x3F803F80u;                                 // dims 16,17: 1,1
    pk2.y = (unsigned int)h1 | ((unsigned int)h2 << 16); // dims 18,19: h1,h2
    pk2.z = 0u; pk2.w = 0u;
    pk3.x = 0u; pk3.y = 0u; pk3.z = 0u; pk3.w = 0u;
    uint4* dst = (uint4*)(tbf32 + (long)rank * 32);
    dst[0] = pk0; dst[1] = pk1; dst[2] = pk2; dst[3] = pk3;
  }
}

// ---------------- Kernel 3: MFMA strip screening (2048 blocks x 256) ---------
// wave = (strip of 32 ranks) x (seg of 512 codes); wave-wide min of FULL d2
// values — zero dependence on lane->(row,col) attribution.
__global__ __launch_bounds__(256, 4) void phase1_kernel(
    const unsigned short* __restrict__ tbf32,
    const unsigned short* __restrict__ cbf32,
    unsigned int* __restrict__ strip_a_u) {
  int tid = threadIdx.x;
  int wave = (int)blockIdx.x * 4 + (tid >> 6);      // 0..8191
  int strip = wave >> 4, seg = wave & 15;
  int l = tid & 63, lr = l & 15, g = l >> 4;
  int row0 = strip * 32;
  const short8 a0 = *(const short8*)(tbf32 + (long)(row0 + lr) * 32 + g * 8);
  const short8 a1 = *(const short8*)(tbf32 + (long)(row0 + 16 + lr) * 32 + g * 8);
  const f32x4 zero = {0.f, 0.f, 0.f, 0.f};
  float rmin = 3.4e38f;
  int code0 = seg * 512;
#pragma unroll 2
  for (int t = 0; t < 32; ++t) {
    int code = code0 + t * 16 + lr;
    short8 b = *(const short8*)(cbf32 + (long)code * 32 + g * 8);
    f32x4 d0 = __builtin_amdgcn_mfma_f32_16x16x32_bf16(a0, b, zero, 0, 0, 0);
    f32x4 d1 = __builtin_amdgcn_mfma_f32_16x16x32_bf16(a1, b, zero, 0, 0, 0);
    float m0 = fminf(fminf(d0[0], d0[1]), fminf(d0[2], d0[3]));
    float m1 = fminf(fminf(d1[0], d1[1]), fminf(d1[2], d1[3]));
    rmin = fminf(rmin, fminf(m0, m1));
  }
#pragma unroll
  for (int s = 1; s < 64; s <<= 1) rmin = fminf(rmin, __shfl_xor(rmin, s));
  if (l == 0) atomicMin(&strip_a_u[strip], encf(rmin));
}

// ---------------- Kernel 4: gate strips, build candidate list ----------------
__global__ __launch_bounds__(512) void reduce_kernel(
    const unsigned int* __restrict__ strip_a_u,
    const unsigned int* __restrict__ stripmax_u,
    const float* __restrict__ pmax_c2,
    unsigned int* __restrict__ candcount, int* __restrict__ candlist) {
  __shared__ float sT[512];
  int tid = threadIdx.x;
  float c2m = 0.f;
#pragma unroll
  for (int i = 0; i < 16; ++i) c2m = fmaxf(c2m, pmax_c2[i]);
  float A   = decf(strip_a_u[tid]);
  float t2m = __uint_as_float(stripmax_u[tid]);
  float eps = fmaf(EPS_C, sqrtf(t2m * c2m), EPS_ABS);
  sT[tid] = A + eps;                                 // NaN ignored by fminf
  __syncthreads();
  for (int st = 256; st > 0; st >>= 1) {
    if (tid < st) sT[tid] = fminf(sT[tid], sT[tid + st]);
    __syncthreads();
  }
  float T = sT[0];
  if (!(A - eps > T)) {                              // NaN-safe: NaN -> pass
    unsigned int pos = atomicAdd(candcount, 1u);
    candlist[pos] = tid;
  }
}

// ---------------- Kernel 5: exact rescore + fused emit (2048 x 256) ----------
// block = (candidate strip, quarter of 8 ranks); wave handles 2 ranks.
__global__ __launch_bounds__(256) void rescore_kernel(
    const float* __restrict__ x, const float* __restrict__ W,
    const float* __restrict__ cbk, const float* __restrict__ c2,
    const int* __restrict__ origrow, const unsigned int* __restrict__ candcount,
    const int* __restrict__ candlist, unsigned long long* __restrict__ key,
    unsigned int* __restrict__ resctr, int* __restrict__ out) {
  int tid = threadIdx.x, bid = (int)blockIdx.x;
  int cidx = bid >> 2, quarter = bid & 3;
  if (cidx < (int)candcount[0]) {
    int strip = candlist[cidx];
    int wv = tid >> 6, l = tid & 63, ch = l & 3;
    int rankA = strip * 32 + quarter * 8 + wv * 2;
    int rankB = rankA + 1;
    float pdA[16], pdB[16];
    proj_row(x, W, origrow[rankA], ch, pdA);
    proj_row(x, W, origrow[rankB], ch, pdB);
    float t2A = 0.f, t2B = 0.f;
#pragma unroll
    for (int c = 0; c < 16; ++c) { t2A = fmaf(pdA[c], pdA[c], t2A);
                                   t2B = fmaf(pdB[c], pdB[c], t2B); }
    float tmA[16], tmB[16];
#pragma unroll
    for (int c = 0; c < 16; ++c) { tmA[c] = -2.0f * pdA[c];
                                   tmB[c] = -2.0f * pdB[c]; }
    float minvA = 3.4e38f, minvB = 3.4e38f; int minkA = 0, minkB = 0;
    for (int j = 0; j < 128; ++j) {
      int code = j * 64 + l;
      const float4* cp = (const float4*)(cbk + (long)code * CDIM);
      float4 c0 = cp[0], c1 = cp[1], c2v4 = cp[2], c3 = cp[3];
      float cc = c2[code];
      float aA = fmaf(tmA[0],  c0.x, cc);
      aA = fmaf(tmA[1],  c0.y, aA);   aA = fmaf(tmA[2],  c0.z, aA);
      aA = fmaf(tmA[3],  c0.w, aA);   aA = fmaf(tmA[4],  c1.x, aA);
      aA = fmaf(tmA[5],  c1.y, aA);   aA = fmaf(tmA[6],  c1.z, aA);
      aA = fmaf(tmA[7],  c1.w, aA);   aA = fmaf(tmA[8],  c2v4.x, aA);
      aA = fmaf(tmA[9],  c2v4.y, aA); aA = fmaf(tmA[10], c2v4.z, aA);
      aA = fmaf(tmA[11], c2v4.w, aA); aA = fmaf(tmA[12], c3.x, aA);
      aA = fmaf(tmA[13], c3.y, aA);   aA = fmaf(tmA[14], c3.z, aA);
      aA = fmaf(tmA[15], c3.w, aA);
      float aB = fmaf(tmB[0],  c0.x, cc);
      aB = fmaf(tmB[1],  c0.y, aB);   aB = fmaf(tmB[2],  c0.z, aB);
      aB = fmaf(tmB[3],  c0.w, aB);   aB = fmaf(tmB[4],  c1.x, aB);
      aB = fmaf(tmB[5],  c1.y, aB);   aB = fmaf(tmB[6],  c1.z, aB);
      aB = fmaf(tmB[7],  c1.w, aB);   aB = fmaf(tmB[8],  c2v4.x, aB);
      aB = fmaf(tmB[9],  c2v4.y, aB); aB = fmaf(tmB[10], c2v4.z, aB);
      aB = fmaf(tmB[11], c2v4.w, aB); aB = fmaf(tmB[12], c3.x, aB);
      aB = fmaf(tmB[13], c3.y, aB);   aB = fmaf(tmB[14], c3.z, aB);
      aB = fmaf(tmB[15], c3.w, aB);
      if (aA < minvA) { minvA = aA; minkA = code; }
      if (aB < minvB) { minvB = aB; minkB = code; }
    }
    unsigned long long packA = ((unsigned long long)encf(t2A + minvA) << 32)
        | (unsigned long long)((unsigned int)rankA * (unsigned int)NCODES + (unsigned int)minkA);
    unsigned long long packB = ((unsigned long long)encf(t2B + minvB) << 32)
        | (unsigned long long)((unsigned int)rankB * (unsigned int)NCODES + (unsigned int)minkB);
    unsigned long long best = (packA < packB) ? packA : packB;
#pragma unroll
    for (int s = 1; s < 64; s <<= 1) {
      unsigned long long o = __shfl_xor(best, s);
      best = (o < best) ? o : best;
    }
    if (l == 0) atomicMin(key, best);
  }
  __syncthreads();
  if (tid == 0) {
    __threadfence();
    if (atomicAdd(resctr, 1u) == (unsigned int)gridDim.x - 1u) {
      unsigned long long v = atomicMin(key, 0xFFFFFFFFFFFFFFFFull);
      out[0] = (int)(unsigned int)(v & 0xFFFFFFFFull);
    }
  }
}

extern "C" void kernel_launch(void* const* d_in, const int* in_sizes, int n_in,
                              void* d_out, int out_size, void* d_ws, size_t ws_size,
                              hipStream_t stream) {
  const float* x    = (const float*)d_in[0];
  const int*   mask = (const int*)d_in[1];
  const float* W    = (const float*)d_in[2];
  const float* cbk  = (const float*)d_in[3];
  int* out = (int*)d_out;

  char* ws = (char*)d_ws;                                   // total 1,687,552 B
  unsigned int*       chunksum  = (unsigned int*)(ws);              // 2048
  int*                chunkpref = (int*)(ws + 2048);                // 2048
  unsigned int*       prepctr   = (unsigned int*)(ws + 4096);       // 4
  unsigned int*       resctr    = (unsigned int*)(ws + 4100);       // 4
  unsigned int*       candcount = (unsigned int*)(ws + 4104);       // 4
  unsigned long long* key       = (unsigned long long*)(ws + 4112); // 8
  float*              pmax_c2   = (float*)(ws + 4128);              // 64
  unsigned int*       strip_a_u = (unsigned int*)(ws + 8192);       // 2048
  unsigned int*       stripmax_u= (unsigned int*)(ws + 10240);      // 2048
  int*                candlist  = (int*)(ws + 12288);               // 2048
  float*              c2        = (float*)(ws + 16384);             // 32 KiB
  int*                origrow   = (int*)(ws + 49152);               // 64 KiB
  unsigned short*     cbf32     = (unsigned short*)(ws + 114688);   // 512 KiB
  unsigned short*     tbf32     = (unsigned short*)(ws + 638976);   // 1 MiB

  hipMemsetAsync(ws + 4096, 0, 12, stream);   // prepctr, resctr, candcount
  prep_kernel<<<80, 512, 0, stream>>>(mask, cbk, chunksum, chunkpref, c2, cbf32,
                                      pmax_c2, strip_a_u, stripmax_u, key, prepctr);
  project_kernel<<<512, 256, 0, stream>>>(x, mask, chunkpref, W, tbf32, origrow,
                                          stripmax_u);
  phase1_kernel<<<2048, 256, 0, stream>>>(tbf32, cbf32, strip_a_u);
  reduce_kernel<<<1, 512, 0, stream>>>(strip_a_u, stripmax_u, pmax_c2,
                                       candcount, candlist);
  rescore_kernel<<<2048, 256, 0, stream>>>(x, W, cbk, c2, origrow, candcount,
                                           candlist, key, resctr, out);
}